// Round 3
// baseline (5088.615 us; speedup 1.0000x reference)
//
#include <hip/hip_runtime.h>
#include <hip/hip_bf16.h>
#include <cstdint>
#include <cstddef>

#define B_ 32
#define T_ 128
#define H_ 1024
#define V_ 32000

using bf16 = __hip_bfloat16;
typedef __attribute__((ext_vector_type(8))) short short8;
typedef __attribute__((ext_vector_type(4))) float f32x4;

__device__ __forceinline__ float bf2f(unsigned short u) {
    return __uint_as_float(((unsigned)u) << 16);
}

__device__ __forceinline__ void lds_cp16(const void* g, void* l) {
    __builtin_amdgcn_global_load_lds(
        (const __attribute__((address_space(1))) unsigned int*)g,
        (__attribute__((address_space(3))) unsigned int*)l, 16, 0, 0);
}

// ---------------------------------------------------------------------------
// f32 -> bf16 conversion, 8 elements/thread, n8 = element_count/8
__global__ __launch_bounds__(256)
void conv_kernel(const float* __restrict__ src, bf16* __restrict__ dst, int n8) {
    int i = blockIdx.x * 256 + threadIdx.x;
    if (i >= n8) return;
    const float4* s = (const float4*)(src + (size_t)i * 8);
    float4 a = s[0], b = s[1];
    ushort4 o0, o1;
    o0.x = __bfloat16_as_ushort(__float2bfloat16(a.x));
    o0.y = __bfloat16_as_ushort(__float2bfloat16(a.y));
    o0.z = __bfloat16_as_ushort(__float2bfloat16(a.z));
    o0.w = __bfloat16_as_ushort(__float2bfloat16(a.w));
    o1.x = __bfloat16_as_ushort(__float2bfloat16(b.x));
    o1.y = __bfloat16_as_ushort(__float2bfloat16(b.y));
    o1.z = __bfloat16_as_ushort(__float2bfloat16(b.z));
    o1.w = __bfloat16_as_ushort(__float2bfloat16(b.w));
    ((ushort4*)(dst + (size_t)i * 8))[0] = o0;
    ((ushort4*)(dst + (size_t)i * 8))[1] = o1;
}

// ---------------------------------------------------------------------------
// init_h: f32 initial states -> fp32 state buffers (parity 0)
__global__ __launch_bounds__(256)
void init_h_kernel(const float* __restrict__ h1, const float* __restrict__ h2,
                   const float* __restrict__ h3, float* __restrict__ Hst) {
    int idx = blockIdx.x * 256 + threadIdx.x;   // < 3*32768
    int layer = idx >> 15;
    int r = idx & 32767;
    const float* src = (layer == 0 ? h1 : (layer == 1 ? h2 : h3));
    Hst[layer * 65536 + r] = src[r];
}

// ---------------------------------------------------------------------------
// embed: X[t*B+b][0:1024] = bf16(word_emb[token]), [1024:2048] = bf16(cat_emb[cat])
// 256 threads x 8 floats = 2048 elements per row (full row)
__global__ __launch_bounds__(256)
void embed_kernel(const int* __restrict__ tok, const int* __restrict__ cat,
                  const float* __restrict__ wemb, const float* __restrict__ cemb,
                  bf16* __restrict__ X) {
    const int tb = blockIdx.x;          // t*32 + b
    const int t = tb >> 5, b = tb & 31;
    const int token = tok[b * T_ + t];
    const int c = cat[b * T_ + t];
    const int i = threadIdx.x;          // 256 chunks of 8 floats
    const float* src = (i < 128) ? (wemb + (size_t)token * H_ + (size_t)i * 8)
                                 : (cemb + (size_t)c * H_ + (size_t)(i - 128) * 8);
    float4 a = ((const float4*)src)[0];
    float4 bv = ((const float4*)src)[1];
    ushort4 o0, o1;
    o0.x = __bfloat16_as_ushort(__float2bfloat16(a.x));
    o0.y = __bfloat16_as_ushort(__float2bfloat16(a.y));
    o0.z = __bfloat16_as_ushort(__float2bfloat16(a.z));
    o0.w = __bfloat16_as_ushort(__float2bfloat16(a.w));
    o1.x = __bfloat16_as_ushort(__float2bfloat16(bv.x));
    o1.y = __bfloat16_as_ushort(__float2bfloat16(bv.y));
    o1.z = __bfloat16_as_ushort(__float2bfloat16(bv.z));
    o1.w = __bfloat16_as_ushort(__float2bfloat16(bv.w));
    ushort4* d = (ushort4*)(X + (size_t)tb * 2 * H_ + (size_t)i * 8);
    d[0] = o0;
    d[1] = o1;
}

// ---------------------------------------------------------------------------
// MFMA GEMM: C[M,N] = A[M,K] @ Bm[N,K]^T + bias[N]   (A,Bm bf16; bias f32)
// MODE 0: Cf fp32 row-major [M,N]
// MODE 1: Cf fp32 scattered: row r=(t*B+b) -> Cf[(b*T+t)*N + col]
template<int MODE>
__global__ __launch_bounds__(256)
void gemm_bt(const bf16* __restrict__ A, const bf16* __restrict__ Bm,
             const float* __restrict__ bias, float* __restrict__ Cf,
             int M, int N, int K) {
    __shared__ __align__(16) bf16 As[128 * 64];
    __shared__ __align__(16) bf16 Bs[128 * 64];
    const int tid = threadIdx.x;
    const int lane = tid & 63;
    const int wid = tid >> 6;
    const int row0 = blockIdx.x * 128;
    const int col0 = blockIdx.y * 128;
    const int rw0 = (wid >> 1) * 64;
    const int cw0 = (wid & 1) * 64;
    const int lr = lane & 15;
    const int lg = lane >> 4;
    f32x4 acc[4][4] = {};
    const int nk = K >> 6;
    for (int kt = 0; kt < nk; ++kt) {
        const int k0 = kt * 64;
#pragma unroll
        for (int i = 0; i < 4; ++i) {
            int c = i * 256 + tid;          // chunk 0..1023
            int r = c >> 3;                 // tile row 0..127
            int kc = (c & 7) * 8;           // k offset in tile
            lds_cp16(A + (size_t)(row0 + r) * K + (k0 + kc), (void*)(As + c * 8));
            lds_cp16(Bm + (size_t)(col0 + r) * K + (k0 + kc), (void*)(Bs + c * 8));
        }
        __syncthreads();
#pragma unroll
        for (int s = 0; s < 2; ++s) {
            short8 af[4], bfr[4];
#pragma unroll
            for (int m = 0; m < 4; ++m)
                af[m] = *(const short8*)(As + (rw0 + m * 16 + lr) * 64 + s * 32 + lg * 8);
#pragma unroll
            for (int n = 0; n < 4; ++n)
                bfr[n] = *(const short8*)(Bs + (cw0 + n * 16 + lr) * 64 + s * 32 + lg * 8);
#pragma unroll
            for (int m = 0; m < 4; ++m)
#pragma unroll
                for (int n = 0; n < 4; ++n)
                    acc[m][n] = __builtin_amdgcn_mfma_f32_16x16x32_bf16(af[m], bfr[n], acc[m][n], 0, 0, 0);
        }
        __syncthreads();
    }
    // epilogue: D[col=lane&15, row=(lane>>4)*4+i] per 16x16 frag (m89-verified)
#pragma unroll
    for (int m = 0; m < 4; ++m) {
#pragma unroll
        for (int n = 0; n < 4; ++n) {
#pragma unroll
            for (int i = 0; i < 4; ++i) {
                int r = row0 + rw0 + m * 16 + lg * 4 + i;
                int cc = col0 + cw0 + n * 16 + lr;
                float v = acc[m][n][i] + bias[cc];
                if (MODE == 0) {
                    Cf[(size_t)r * N + cc] = v;
                } else {
                    int b = r & 31, t = r >> 5;
                    Cf[((size_t)b * T_ + t) * (size_t)N + cc] = v;
                }
            }
        }
    }
}

// ---------------------------------------------------------------------------
// One recurrence step of one layer.
// GI [T*B][3H] fp32 (includes bih). gh computed here (fp32 dots, bf16 weights).
// grid 512: blockIdx -> (bg = blk&3: 8 batches, ub = blk>>2: 8 units)
// block 512: tid -> (q = tid>>6: k-split 8, u = (tid>>3)&7, b = tid&7)
__global__ __launch_bounds__(512)
void rec_step(const float* __restrict__ GI, const bf16* __restrict__ Whh,
              const float* __restrict__ bhh, const float* __restrict__ hin,
              float* __restrict__ hout, bf16* __restrict__ Cb, int t) {
    __shared__ float hlds[8 * 1028];
    __shared__ float plds[8][8][8][3];
    const int tid = threadIdx.x;
    const int bg = blockIdx.x & 3;
    const int ub = blockIdx.x >> 2;
    // stage 8 h rows (fp32), padded stride 1028
    for (int c = tid * 4; c < 8 * 1024; c += 512 * 4) {
        int br = c >> 10, k = c & 1023;
        float4 v = *(const float4*)(hin + (size_t)(bg * 8 + br) * H_ + k);
        *(float4*)&hlds[br * 1028 + k] = v;
    }
    __syncthreads();
    const int q = tid >> 6;
    const int u = (tid >> 3) & 7;
    const int b = tid & 7;
    const int ug = ub * 8 + u;
    const unsigned short* w = (const unsigned short*)Whh;
    const unsigned short* wr = w + (size_t)ug * H_;
    const unsigned short* wz = w + (size_t)(H_ + ug) * H_;
    const unsigned short* wn = w + (size_t)(2 * H_ + ug) * H_;
    const float* hrow = &hlds[b * 1028];
    float sr = 0.f, sz = 0.f, sn = 0.f;
    const int kb = q * 128;
#pragma unroll 8
    for (int k = kb; k < kb + 128; k += 4) {
        float4 h4 = *(const float4*)(hrow + k);
        ushort4 a = *(const ushort4*)(wr + k);
        ushort4 c4 = *(const ushort4*)(wz + k);
        ushort4 d4 = *(const ushort4*)(wn + k);
        sr += bf2f(a.x) * h4.x + bf2f(a.y) * h4.y + bf2f(a.z) * h4.z + bf2f(a.w) * h4.w;
        sz += bf2f(c4.x) * h4.x + bf2f(c4.y) * h4.y + bf2f(c4.z) * h4.z + bf2f(c4.w) * h4.w;
        sn += bf2f(d4.x) * h4.x + bf2f(d4.y) * h4.y + bf2f(d4.z) * h4.z + bf2f(d4.w) * h4.w;
    }
    plds[q][u][b][0] = sr;
    plds[q][u][b][1] = sz;
    plds[q][u][b][2] = sn;
    __syncthreads();
    if (q == 0) {
        float tr = bhh[ug];
        float tz = bhh[H_ + ug];
        float tn = bhh[2 * H_ + ug];
#pragma unroll
        for (int qq = 0; qq < 8; ++qq) {
            tr += plds[qq][u][b][0];
            tz += plds[qq][u][b][1];
            tn += plds[qq][u][b][2];
        }
        const int bglob = bg * 8 + b;
        const float* gi = GI + ((size_t)t * B_ + bglob) * 3072;
        float rr = 1.f / (1.f + expf(-(gi[ug] + tr)));
        float zz = 1.f / (1.f + expf(-(gi[H_ + ug] + tz)));
        float nn = tanhf(gi[2 * H_ + ug] + rr * tn);
        float hold = hlds[b * 1028 + ug];
        float hnew = (1.f - zz) * nn + zz * hold;
        hout[(size_t)bglob * H_ + ug] = hnew;
        Cb[((size_t)t * B_ + bglob) * H_ + ug] = __float2bfloat16(hnew);
    }
}

// ---------------------------------------------------------------------------
// final hidden states -> output tail (f32), parity 0 after 128 steps
__global__ __launch_bounds__(256)
void final_out_kernel(const float* __restrict__ Hst, float* __restrict__ outt) {
    int idx = blockIdx.x * 256 + threadIdx.x;   // < 3*32768
    int layer = idx >> 15;
    int r = idx & 32767;
    outt[idx] = Hst[layer * 65536 + r];
}

// ---------------------------------------------------------------------------
extern "C" void kernel_launch(void* const* d_in, const int* in_sizes, int n_in,
                              void* d_out, int out_size, void* d_ws, size_t ws_size,
                              hipStream_t stream) {
    const int* tok = (const int*)d_in[0];
    const int* cat = (const int*)d_in[1];
    // d_in[2] = batch_size (unused)
    const float* h1 = (const float*)d_in[3];
    const float* h2 = (const float*)d_in[4];
    const float* h3 = (const float*)d_in[5];
    const float* wemb = (const float*)d_in[6];
    const float* cemb = (const float*)d_in[7];
    const float* Wih[3] = {(const float*)d_in[8], (const float*)d_in[12], (const float*)d_in[16]};
    const float* Whh[3] = {(const float*)d_in[9], (const float*)d_in[13], (const float*)d_in[17]};
    const float* bih[3] = {(const float*)d_in[10], (const float*)d_in[14], (const float*)d_in[18]};
    const float* bhh[3] = {(const float*)d_in[11], (const float*)d_in[15], (const float*)d_in[19]};
    const float* fcw = (const float*)d_in[20];
    const float* fcb = (const float*)d_in[21];
    float* out = (float*)d_out;

    // workspace layout (bytes): see round-1 comment; peak 137,101,312
    char* ws = (char*)d_ws;
    bf16* C3 = (bf16*)ws;
    bf16* Xbf = (bf16*)(ws + 8388608);
    bf16* C1 = (bf16*)(ws + 25165824);
    bf16* C2 = (bf16*)(ws + 33554432);
    float* GI = (float*)(ws + 41943040);
    bf16* fcwB = (bf16*)(ws + 8388608);       // reclaims Xbf/C1/C2/GI after rec3
    float* Hst = (float*)(ws + 92274688);
    bf16* WihB[3] = {(bf16*)(ws + 93061120), (bf16*)(ws + 105644032), (bf16*)(ws + 111935488)};
    bf16* WhhB[3] = {(bf16*)(ws + 118226944), (bf16*)(ws + 124518400), (bf16*)(ws + 130809856)};
    bf16* Cs[3] = {C1, C2, C3};

    // weight conversions (f32 -> bf16)
    conv_kernel<<<3072, 256, 0, stream>>>(Wih[0], WihB[0], 786432);
    conv_kernel<<<1536, 256, 0, stream>>>(Wih[1], WihB[1], 393216);
    conv_kernel<<<1536, 256, 0, stream>>>(Wih[2], WihB[2], 393216);
    conv_kernel<<<1536, 256, 0, stream>>>(Whh[0], WhhB[0], 393216);
    conv_kernel<<<1536, 256, 0, stream>>>(Whh[1], WhhB[1], 393216);
    conv_kernel<<<1536, 256, 0, stream>>>(Whh[2], WhhB[2], 393216);

    init_h_kernel<<<384, 256, 0, stream>>>(h1, h2, h3, Hst);
    embed_kernel<<<T_ * B_, 256, 0, stream>>>(tok, cat, wemb, cemb, Xbf);

    for (int layer = 0; layer < 3; ++layer) {
        const bf16* Ain = (layer == 0) ? Xbf : Cs[layer - 1];
        int K = (layer == 0) ? 2048 : 1024;
        gemm_bt<0><<<dim3(32, 24), 256, 0, stream>>>(Ain, WihB[layer], bih[layer],
                                                     GI, 4096, 3072, K);
        float* hbase = Hst + layer * 65536;
        for (int t = 0; t < 128; ++t) {
            const float* hin = hbase + (t & 1) * 32768;
            float* hout = hbase + ((t + 1) & 1) * 32768;
            rec_step<<<512, 512, 0, stream>>>(GI, WhhB[layer], bhh[layer], hin, hout,
                                              Cs[layer], t);
        }
    }
    // fc_w conversion into reclaimed workspace, then FC GEMM straight to d_out
    conv_kernel<<<16000, 256, 0, stream>>>(fcw, fcwB, 4096000);
    gemm_bt<1><<<dim3(32, 250), 256, 0, stream>>>(C3, fcwB, fcb, out, 4096, 32000, 1024);
    final_out_kernel<<<384, 256, 0, stream>>>(Hst, out + (size_t)B_ * T_ * V_);
}